// Round 16
// baseline (178.892 us; speedup 1.0000x reference)
//
#include <hip/hip_runtime.h>
#include <math.h>

// HardMoE classifier: B=131072, D=1024, E=6, L=2, fp32.
// Skinny-GEMM MFMA: [B,1024] @ [1024,18 used cols] in two 16-col bf16
// panels (cols 0-5 gate, 6-17 expert), 2 mfma_16x16x32_bf16 per k-step.
// r15 = 169us: unroll-2 loop state + epilogue likely pushed VGPR > 128
// -> 8 waves/CU, per-iter vmcnt stall exposed (~1000cyc HBM latency,
// only 2 waves/SIMD to cover it). r16: explicit 1-deep A prefetch with
// unroll 1 (live set ~36 regs in loop) -> target VGPR <= 128, 16 waves/CU,
// one 2KB load-pair always in flight per wave (32KB/CU outstanding).
// Epilogue/fallback identical to r15 (validated: absmax .015625).
// LESSON (r2/r8): no min-waves launch_bounds arg.

typedef __attribute__((ext_vector_type(8))) short short8;
typedef __attribute__((ext_vector_type(4))) float f32x4;
typedef __attribute__((ext_vector_type(4))) unsigned int uint4v;

static constexpr int En = 6;

template <int CTRL>
__device__ __forceinline__ float dpp_row_add(float v) {
  return v + __int_as_float(__builtin_amdgcn_update_dpp(
                 0, __float_as_int(v), CTRL, 0xf, 0xf, true));
}

__device__ __forceinline__ float wave_sum_bcast(float v) {
  v = dpp_row_add<0x111>(v);
  v = dpp_row_add<0x112>(v);
  v = dpp_row_add<0x114>(v);
  v = dpp_row_add<0x118>(v);
  v = dpp_row_add<0x142>(v);
  v = dpp_row_add<0x143>(v);
  return __int_as_float(__builtin_amdgcn_readlane(__float_as_int(v), 63));
}

__device__ __forceinline__ ushort f2bf(float f) {  // RNE float->bf16
  unsigned u = __float_as_uint(f);
  u += 0x7FFFu + ((u >> 16) & 1u);
  return (ushort)(u >> 16);
}

// Pack two floats to packed bf16x2 (round-half-up; tie deviations from RNE
// are covered by the near-tie fallback threshold). Validated r15.
__device__ __forceinline__ unsigned pack2(float lo, float hi) {
  const unsigned a = __float_as_uint(lo) + 0x8000u;
  const unsigned b = __float_as_uint(hi) + 0x8000u;
  return (b & 0xFFFF0000u) | (a >> 16);
}

__global__ __launch_bounds__(512) void hardmoe_mfma(
    const float* __restrict__ cls, const float* __restrict__ gate_w,
    const float* __restrict__ gate_b, const float* __restrict__ expert_w,
    const float* __restrict__ expert_b, float* __restrict__ out) {
  // Two B panels: [kc 0..127][col 0..15][k7 0..7] bf16, k = kc*8+k7.
  // Panel p holds global cols p*16..p*16+15. 32768 ushort = 64 KB.
  __shared__ ushort ldsB[32768];

  const int tid = threadIdx.x;
  const int lane = tid & 63;
  const int wv = tid >> 6;

  for (int i = tid; i < 32768; i += 512) {
    const int p = i >> 14;
    const int r = i & 16383;
    const int k7 = r & 7, col16 = (r >> 3) & 15, kc = r >> 7;
    const int gcol = p * 16 + col16;
    const int k = kc * 8 + k7;
    float v = 0.f;
    if (gcol < 6) v = gate_w[gcol * 1024 + k];
    else if (gcol < 18) v = expert_w[(gcol - 6) * 1024 + k];
    ldsB[i] = f2bf(v);
  }
  float gb[En];
#pragma unroll
  for (int e = 0; e < En; ++e) gb[e] = gate_b[e];  // uniform -> sgpr
  __syncthreads();

  const int g = lane >> 4, cidx = lane & 15;
  const ushort* bbase = ldsB + g * 128 + cidx * 8;

  // Persistent: 512 blocks * 8 waves = 4096 waves; 8192 tiles -> 2 each.
  for (int tile = blockIdx.x * 8 + wv; tile < 8192; tile += 4096) {
    // A: row = tile*16 + cidx, k = kk*32 + g*8 + j (same placement as B).
    const float* arow = cls + (size_t)(tile * 16 + cidx) * 1024 + g * 8;

    f32x4 acc0 = {0.f, 0.f, 0.f, 0.f};
    f32x4 acc1 = {0.f, 0.f, 0.f, 0.f};

    // 1-deep software pipeline: next iteration's loads issue before the
    // current pack+MFMA, so one 2KB load-pair is always in flight.
    float4 ca0 = *(const float4*)(arow);
    float4 ca1 = *(const float4*)(arow + 4);
#pragma unroll 1
    for (int kk = 0; kk < 32; ++kk) {
      const int nk = (kk + 1) & 31;  // last iter: harmless re-read
      const float4 na0 = *(const float4*)(arow + nk * 32);
      const float4 na1 = *(const float4*)(arow + nk * 32 + 4);
      uint4v ap;
      ap.x = pack2(ca0.x, ca0.y);
      ap.y = pack2(ca0.z, ca0.w);
      ap.z = pack2(ca1.x, ca1.y);
      ap.w = pack2(ca1.z, ca1.w);
      const short8 af = __builtin_bit_cast(short8, ap);
      const short8 b0 = *(const short8*)(bbase + kk * 512);
      const short8 b1 = *(const short8*)(bbase + 16384 + kk * 512);
      acc0 = __builtin_amdgcn_mfma_f32_16x16x32_bf16(af, b0, acc0, 0, 0, 0);
      acc1 = __builtin_amdgcn_mfma_f32_16x16x32_bf16(af, b1, acc1, 0, 0, 0);
      ca0 = na0;
      ca1 = na1;
    }

    // ---- epilogue: acc_p[j] = C[row=g*4+j][col=p*16+cidx] ----
    float bv[4], sec[4], o0[4], o1[4];
    int be[4];
#pragma unroll
    for (int j = 0; j < 4; ++j) {
      bv[j] = -INFINITY; sec[j] = -INFINITY; be[j] = 0;
#pragma unroll
      for (int e = 0; e < En; ++e) {
        const float v = __shfl(acc0[j], e, 16) + gb[e];
        if (v > bv[j]) {
          sec[j] = bv[j]; bv[j] = v; be[j] = e;
        } else if (v > sec[j]) {
          sec[j] = v;
        }
      }
      // Expert cols 6+2*be, 7+2*be; be=5 wraps to panel1 cols 0,1.
      const int c0 = (6 + 2 * be[j]) & 15;
      const int c1 = (7 + 2 * be[j]) & 15;
      const float x00 = __shfl(acc0[j], c0, 16);
      const float x10 = __shfl(acc1[j], c0, 16);
      const float x01 = __shfl(acc0[j], c1, 16);
      const float x11 = __shfl(acc1[j], c1, 16);
      o0[j] = (be[j] < 5) ? x00 : x10;
      o1[j] = (be[j] < 5) ? x01 : x11;
    }

    // ---- near-tie fallback (~3%): plain fp32 gate re-dot from global ----
    unsigned long long need = 0;
#pragma unroll
    for (int j = 0; j < 4; ++j) {
      const unsigned long long m =
          __ballot(cidx == 0 && (bv[j] - sec[j] < 0.015f));
#pragma unroll
      for (int g2 = 0; g2 < 4; ++g2)
        if ((m >> (g2 * 16)) & 1) need |= 1ull << (g2 * 4 + j);
    }

    while (need) {
      const int rr = __ffsll((long long)need) - 1;
      need &= need - 1;
      const int rg = rr >> 2, rj = rr & 3;
      const int row = tile * 16 + rr;
      const float4* crow4 = (const float4*)(cls + (size_t)row * 1024);
      const float4* gw4 = (const float4*)gate_w;
      float kb = -INFINITY;
      int ke = 0;
#pragma unroll
      for (int e = 0; e < En; ++e) {
        float sum = 0.f;
#pragma unroll
        for (int t = 0; t < 4; ++t) {
          const float4 cc = crow4[t * 64 + lane];
          const float4 w = gw4[e * 256 + t * 64 + lane];
          sum = fmaf(cc.x, w.x, sum);
          sum = fmaf(cc.y, w.y, sum);
          sum = fmaf(cc.z, w.z, sum);
          sum = fmaf(cc.w, w.w, sum);
        }
        const float v = wave_sum_bcast(sum) + gb[e];
        if (v > kb) { kb = v; ke = e; }
      }
      const float aj0 = (rj == 0) ? acc0[0] : (rj == 1) ? acc0[1]
                      : (rj == 2) ? acc0[2] : acc0[3];
      const float aj1 = (rj == 0) ? acc1[0] : (rj == 1) ? acc1[1]
                      : (rj == 2) ? acc1[2] : acc1[3];
      const int ec0 = 6 + 2 * ke;
      float n0, n1;
      if (ec0 < 16) {  // wave-uniform branch
        n0 = __int_as_float(
            __builtin_amdgcn_readlane(__float_as_int(aj0), rg * 16 + ec0));
        n1 = __int_as_float(
            __builtin_amdgcn_readlane(__float_as_int(aj0), rg * 16 + ec0 + 1));
      } else {
        n0 = __int_as_float(
            __builtin_amdgcn_readlane(__float_as_int(aj1), rg * 16 + 0));
        n1 = __int_as_float(
            __builtin_amdgcn_readlane(__float_as_int(aj1), rg * 16 + 1));
      }
#pragma unroll
      for (int j = 0; j < 4; ++j) {
        const bool upd = (j == rj) && (g == rg);
        o0[j] = upd ? n0 : o0[j];
        o1[j] = upd ? n1 : o1[j];
        be[j] = upd ? ke : be[j];
      }
    }

    // ---- store: lane g*16+c (c<4) stores row tile*16 + g*4 + c ----
    if (cidx < 4) {
      const float s0 = (cidx == 0) ? o0[0] : (cidx == 1) ? o0[1]
                     : (cidx == 2) ? o0[2] : o0[3];
      const float s1 = (cidx == 0) ? o1[0] : (cidx == 1) ? o1[1]
                     : (cidx == 2) ? o1[2] : o1[3];
      const int sb = (cidx == 0) ? be[0] : (cidx == 1) ? be[1]
                   : (cidx == 2) ? be[2] : be[3];
      const int row = tile * 16 + g * 4 + cidx;
      ((float2*)out)[row] =
          make_float2(s0 + expert_b[sb * 2 + 0], s1 + expert_b[sb * 2 + 1]);
    }
  }
}

extern "C" void kernel_launch(void* const* d_in, const int* in_sizes, int n_in,
                              void* d_out, int out_size, void* d_ws,
                              size_t ws_size, hipStream_t stream) {
  const float* cls = (const float*)d_in[0];
  const float* gate_w = (const float*)d_in[1];
  const float* gate_b = (const float*)d_in[2];
  const float* expert_w = (const float*)d_in[3];
  const float* expert_b = (const float*)d_in[4];
  float* out = (float*)d_out;

  // Persistent: 512 blocks * 512 threads = 2 blocks/CU; 2 tiles per wave.
  hipLaunchKernelGGL(hardmoe_mfma, dim3(512), dim3(512), 0, stream, cls,
                     gate_w, gate_b, expert_w, expert_b, out);
}

// Round 17
// 163.124 us; speedup vs baseline: 1.0967x; 1.0967x over previous
//
#include <hip/hip_runtime.h>
#include <math.h>

// HardMoE classifier: B=131072, D=1024, E=6, L=2, fp32.
// Streaming design: loads taken OFF the dependency chain via
// global_load_lds (async HBM->LDS DMA, no VGPR, no barrier), wave-private
// double-buffered row slots. Evidence: r10/r11 (118us) invariant to
// occupancy (16 vs 24 waves) and to reg-prefetch (r7) => loads sat in the
// per-row chain, duty ~10%, 6.5KB in flight/CU = 4.35 TB/s (Little).
// Here: waitcnt(0) drains last iter's loads (issued a full compute phase
// ago -> free), issue next row's 4 loads, compute current from LDS ->
// 4KB/wave continuously in flight, HBM-bound target ~5.2+ TB/s.
// Weights bf16 in LDS (gate 12KB + expert 24KB, validated r12) + 8x2x4KB
// rowbufs = 100.3KB -> 1 block/CU (8 waves). Near-tie (<0.02) fp32 re-dot
// from global (validated r12). MFMA branch abandoned (r13-16: scattered
// 64B A-granules + serial load->pack->MFMA chain, best 169us).
// LESSON (r2/r8): no min-waves launch_bounds arg.

typedef unsigned int u32;
static constexpr int En = 6;

template <int CTRL>
__device__ __forceinline__ float dpp_row_add(float v) {
  return v + __int_as_float(__builtin_amdgcn_update_dpp(
                 0, __float_as_int(v), CTRL, 0xf, 0xf, true));
}

// Full 64-lane sum, broadcast via readlane(63) -> sgpr.
__device__ __forceinline__ float wave_sum_bcast(float v) {
  v = dpp_row_add<0x111>(v);  // row_shr:1
  v = dpp_row_add<0x112>(v);  // row_shr:2
  v = dpp_row_add<0x114>(v);  // row_shr:4
  v = dpp_row_add<0x118>(v);  // row_shr:8
  v = dpp_row_add<0x142>(v);  // row_bcast:15
  v = dpp_row_add<0x143>(v);  // row_bcast:31
  return __int_as_float(__builtin_amdgcn_readlane(__float_as_int(v), 63));
}

__device__ __forceinline__ float dot4(float4 a, float4 b) {
  return fmaf(a.x, b.x, fmaf(a.y, b.y, fmaf(a.z, b.z, a.w * b.w)));
}

__device__ __forceinline__ ushort f2bf(float f) {  // RNE float->bf16
  unsigned u = __float_as_uint(f);
  u += 0x7FFFu + ((u >> 16) & 1u);
  return (ushort)(u >> 16);
}

__device__ __forceinline__ float4 bf2f4(ushort4 u) {
  return make_float4(__uint_as_float(((unsigned)u.x) << 16),
                     __uint_as_float(((unsigned)u.y) << 16),
                     __uint_as_float(((unsigned)u.z) << 16),
                     __uint_as_float(((unsigned)u.w) << 16));
}

// Async global->LDS, 16B per lane. LDS dest is wave-uniform base; HW adds
// lane*16. Completion tracked by vmcnt.
__device__ __forceinline__ void gload16(const float* g, void* l) {
  __builtin_amdgcn_global_load_lds(
      (const __attribute__((address_space(1))) u32*)g,
      (__attribute__((address_space(3))) u32*)l, 16, 0, 0);
}

__global__ __launch_bounds__(512) void hardmoe_stream(
    const float* __restrict__ cls, const float* __restrict__ gate_w,
    const float* __restrict__ gate_b, const float* __restrict__ expert_w,
    const float* __restrict__ expert_b, float* __restrict__ out) {
  __shared__ ushort ldsG[6144];          // gate_w  bf16: 6x1024  = 12 KB
  __shared__ ushort ldsE[12288];         // expert_w bf16: 12x1024 = 24 KB
  __shared__ float ldsGb[6];
  __shared__ float ldsEb[12];
  __shared__ float4 rowbuf[8][2][256];   // 8 waves x 2 bufs x 4KB = 64 KB

  const int tid = threadIdx.x;
  const int lane = tid & 63;
  const int w = tid >> 6;

  {
    const float4* __restrict__ gw4 = (const float4*)gate_w;
    const float4* __restrict__ ew4 = (const float4*)expert_w;
#pragma unroll
    for (int k = 0; k < 3; ++k) {
      const int i = tid + k * 512;
      const float4 v = gw4[i];
      ((ushort4*)ldsG)[i] =
          make_ushort4(f2bf(v.x), f2bf(v.y), f2bf(v.z), f2bf(v.w));
    }
#pragma unroll
    for (int k = 0; k < 6; ++k) {
      const int i = tid + k * 512;
      const float4 v = ew4[i];
      ((ushort4*)ldsE)[i] =
          make_ushort4(f2bf(v.x), f2bf(v.y), f2bf(v.z), f2bf(v.w));
    }
    if (tid < 6) ldsGb[tid] = gate_b[tid];
    else if (tid < 18) ldsEb[tid - 6] = expert_b[tid - 6];
  }
  __syncthreads();

  const ushort4* __restrict__ G4 = (const ushort4*)ldsG;
  const ushort4* __restrict__ E4 = (const ushort4*)ldsE;
  const float4* __restrict__ gw4 = (const float4*)gate_w;

  const int gwid = blockIdx.x * 8 + w;  // 0..2047

  // Prologue: issue row0's 4 loads into buf 0.
  {
    const float* rp = cls + (size_t)gwid * 1024;
#pragma unroll
    for (int i = 0; i < 4; ++i)
      gload16(rp + i * 256 + lane * 4, &rowbuf[w][0][i * 64]);
  }

  for (int it = 0; it < 64; ++it) {
    const int row = gwid + it * 2048;
    // Current row's loads were issued one full compute phase ago.
    asm volatile("s_waitcnt vmcnt(0)" ::: "memory");

    if (it != 63) {  // issue next row's loads into the other buffer
      const float* rp = cls + (size_t)(row + 2048) * 1024;
      const int nb = (it + 1) & 1;
#pragma unroll
      for (int i = 0; i < 4; ++i)
        gload16(rp + i * 256 + lane * 4, &rowbuf[w][nb][i * 64]);
    }

    // Row slice to registers (4 conflict-free ds_read_b128).
    const float4* cb = &rowbuf[w][it & 1][0];
    float4 c[4];
#pragma unroll
    for (int t = 0; t < 4; ++t) c[t] = cb[t * 64 + lane];

    // ---- gate logits (bf16 weights) + fused argmax ----
    int best = 0;
    float bv = -INFINITY, sec = -INFINITY;
#pragma unroll
    for (int e = 0; e < En; ++e) {
      float s = 0.f;
#pragma unroll
      for (int t = 0; t < 4; ++t)
        s += dot4(c[t], bf2f4(G4[e * 256 + t * 64 + lane]));
      const float v = wave_sum_bcast(s) + ldsGb[e];
      if (v > bv) {
        sec = bv; bv = v; best = e;
      } else if (v > sec) {
        sec = v;
      }
    }

    // Near-tie (~3%): fp32 re-dot from global gate_w (L2-hot).
    if (__builtin_expect(bv - sec < 0.02f, 0)) {
      float kb = -INFINITY;
      int ki = 0;
#pragma unroll
      for (int e = 0; e < En; ++e) {
        float sum = 0.f;
#pragma unroll
        for (int t = 0; t < 4; ++t) {
          const float4 cc = c[t];
          const float4 ww = gw4[e * 256 + t * 64 + lane];
          sum = fmaf(cc.x, ww.x, sum);
          sum = fmaf(cc.y, ww.y, sum);
          sum = fmaf(cc.z, ww.z, sum);
          sum = fmaf(cc.w, ww.w, sum);
        }
        const float v = wave_sum_bcast(sum) + ldsGb[e];
        if (v > kb) { kb = v; ki = e; }
      }
      best = ki;
    }

    // ---- chosen expert from bf16 LDS ----
    const ushort4* e4 = E4 + best * 512;
    float a0 = 0.f, a1 = 0.f;
#pragma unroll
    for (int t = 0; t < 4; ++t) {
      a0 += dot4(c[t], bf2f4(e4[t * 64 + lane]));
      a1 += dot4(c[t], bf2f4(e4[256 + t * 64 + lane]));
    }
    const float o0 = wave_sum_bcast(a0) + ldsEb[best * 2 + 0];
    const float o1 = wave_sum_bcast(a1) + ldsEb[best * 2 + 1];
    if (lane == 0) ((float2*)out)[row] = make_float2(o0, o1);
  }
}

extern "C" void kernel_launch(void* const* d_in, const int* in_sizes, int n_in,
                              void* d_out, int out_size, void* d_ws,
                              size_t ws_size, hipStream_t stream) {
  const float* cls = (const float*)d_in[0];
  const float* gate_w = (const float*)d_in[1];
  const float* gate_b = (const float*)d_in[2];
  const float* expert_w = (const float*)d_in[3];
  const float* expert_b = (const float*)d_in[4];
  float* out = (float*)d_out;

  // 256 blocks * 512 threads, 100.3KB LDS -> 1 block/CU; 2048 waves,
  // 64 rows each (exact).
  hipLaunchKernelGGL(hardmoe_stream, dim3(256), dim3(512), 0, stream, cls,
                     gate_w, gate_b, expert_w, expert_b, out);
}

// Round 18
// 149.576 us; speedup vs baseline: 1.1960x; 1.0906x over previous
//
#include <hip/hip_runtime.h>
#include <math.h>

// HardMoE classifier: B=131072, D=1024, E=6, L=2, fp32.
// r18 = r10 (bf16 weights in LDS, 118.2us) + r7's R=2 row pairing (122.8us
// with fp32 weights). The two validated wins are orthogonal:
//  - pairing halves per-row LDS weight reads (192->~120 cyc/row) and
//    interleaves two rows' DPP reduction chains (8 serial -> 4 + ILP);
//  - bf16 weights halve LDS bytes (validated absmax .0156 << .061).
// VGPR ~75 (c[2][4]=32 + accums) -> no occupancy cliff; LDS 36.3KB.
// Near-tie (<0.02, ~3%) plain-fp32 re-dot from global (validated r17).
// Structural alternatives all lost: MFMA 169-222 (scattered A-granules),
// async global_load_lds 163 (1 blk/CU, 8 waves). LESSON (r2/r8): no
// min-waves launch_bounds arg.

static constexpr int En = 6;
static constexpr int NPAIR = 65536;  // 131072 / 2
static constexpr int NW = 4096;      // 512 blocks * 8 waves

template <int CTRL>
__device__ __forceinline__ float dpp_row_add(float v) {
  return v + __int_as_float(__builtin_amdgcn_update_dpp(
                 0, __float_as_int(v), CTRL, 0xf, 0xf, true));
}

// Full 64-lane sum, broadcast via readlane(63) -> sgpr.
__device__ __forceinline__ float wave_sum_bcast(float v) {
  v = dpp_row_add<0x111>(v);  // row_shr:1
  v = dpp_row_add<0x112>(v);  // row_shr:2
  v = dpp_row_add<0x114>(v);  // row_shr:4
  v = dpp_row_add<0x118>(v);  // row_shr:8
  v = dpp_row_add<0x142>(v);  // row_bcast:15
  v = dpp_row_add<0x143>(v);  // row_bcast:31
  return __int_as_float(__builtin_amdgcn_readlane(__float_as_int(v), 63));
}

__device__ __forceinline__ float dot4(float4 a, float4 b) {
  return fmaf(a.x, b.x, fmaf(a.y, b.y, fmaf(a.z, b.z, a.w * b.w)));
}

__device__ __forceinline__ ushort f2bf(float f) {  // RNE float->bf16
  unsigned u = __float_as_uint(f);
  u += 0x7FFFu + ((u >> 16) & 1u);
  return (ushort)(u >> 16);
}

__device__ __forceinline__ float4 bf2f4(ushort4 u) {
  return make_float4(__uint_as_float(((unsigned)u.x) << 16),
                     __uint_as_float(((unsigned)u.y) << 16),
                     __uint_as_float(((unsigned)u.z) << 16),
                     __uint_as_float(((unsigned)u.w) << 16));
}

__global__ __launch_bounds__(512) void hardmoe_kernel(
    const float* __restrict__ cls, const float* __restrict__ gate_w,
    const float* __restrict__ gate_b, const float* __restrict__ expert_w,
    const float* __restrict__ expert_b, float* __restrict__ out) {
  // Layout-preserving bf16: ushort4 index i == float4 index i of fp32
  // original, so the read pattern [e*256 + t*64 + lane] matches c[t].
  __shared__ ushort4 ldsG16[1536];  // gate_w  bf16: 6x1024   = 12 KB
  __shared__ ushort4 ldsE16[3072];  // expert_w bf16: 12x1024 = 24 KB
  __shared__ float ldsGb[6];
  __shared__ float ldsEb[12];

  const int tid = threadIdx.x;
  const int lane = tid & 63;

  {
    const float4* __restrict__ gw4s = (const float4*)gate_w;
    const float4* __restrict__ ew4 = (const float4*)expert_w;
#pragma unroll
    for (int k = 0; k < 3; ++k) {
      const int i = tid + k * 512;
      const float4 v = gw4s[i];
      ldsG16[i] = make_ushort4(f2bf(v.x), f2bf(v.y), f2bf(v.z), f2bf(v.w));
    }
#pragma unroll
    for (int k = 0; k < 6; ++k) {
      const int i = tid + k * 512;
      const float4 v = ew4[i];
      ldsE16[i] = make_ushort4(f2bf(v.x), f2bf(v.y), f2bf(v.z), f2bf(v.w));
    }
    if (tid < 6) ldsGb[tid] = gate_b[tid];
    else if (tid < 18) ldsEb[tid - 6] = expert_b[tid - 6];
  }
  __syncthreads();

  const float4* __restrict__ cls4 = (const float4*)cls;
  const float4* __restrict__ gw4 = (const float4*)gate_w;
  const int gwid = blockIdx.x * 8 + (tid >> 6);

  for (int pp = gwid; pp < NPAIR; pp += NW) {
    const int row = pp * 2;
    float4 c[2][4];
#pragma unroll
    for (int rr = 0; rr < 2; ++rr)
#pragma unroll
      for (int t = 0; t < 4; ++t)
        c[rr][t] = cls4[(size_t)(row + rr) * 256 + t * 64 + lane];

    // ---- gate logits: pair shares each bf16 weight read ----
    int best[2] = {0, 0};
    float bv[2] = {-INFINITY, -INFINITY}, sec[2] = {-INFINITY, -INFINITY};
#pragma unroll
    for (int e = 0; e < En; ++e) {
      float s0 = 0.f, s1 = 0.f;
#pragma unroll
      for (int t = 0; t < 4; ++t) {
        const float4 W = bf2f4(ldsG16[e * 256 + t * 64 + lane]);
        s0 += dot4(c[0][t], W);
        s1 += dot4(c[1][t], W);
      }
      const float gb = ldsGb[e];
      const float v0 = wave_sum_bcast(s0) + gb;  // two independent chains
      const float v1 = wave_sum_bcast(s1) + gb;  // interleave on the SIMD
      if (v0 > bv[0]) {
        sec[0] = bv[0]; bv[0] = v0; best[0] = e;
      } else if (v0 > sec[0]) {
        sec[0] = v0;
      }
      if (v1 > bv[1]) {
        sec[1] = bv[1]; bv[1] = v1; best[1] = e;
      } else if (v1 > sec[1]) {
        sec[1] = v1;
      }
    }

    // ---- near-tie fallback (~3%): plain fp32 re-dot from global ----
#pragma unroll
    for (int rr = 0; rr < 2; ++rr) {
      if (__builtin_expect(bv[rr] - sec[rr] < 0.02f, 0)) {
        float kb = -INFINITY;
        int ki = 0;
#pragma unroll
        for (int e = 0; e < En; ++e) {
          float sum = 0.f;
#pragma unroll
          for (int t = 0; t < 4; ++t) {
            const float4 cc = c[rr][t];
            const float4 ww = gw4[e * 256 + t * 64 + lane];
            sum = fmaf(cc.x, ww.x, sum);
            sum = fmaf(cc.y, ww.y, sum);
            sum = fmaf(cc.z, ww.z, sum);
            sum = fmaf(cc.w, ww.w, sum);
          }
          const float v = wave_sum_bcast(sum) + ldsGb[e];
          if (v > kb) { kb = v; ki = e; }
        }
        best[rr] = ki;
      }
    }

    // ---- chosen experts from bf16 LDS (two rows interleave) ----
    const ushort4* e40 = ldsE16 + best[0] * 512;
    const ushort4* e41 = ldsE16 + best[1] * 512;
    float a00 = 0.f, a01 = 0.f, a10 = 0.f, a11 = 0.f;
#pragma unroll
    for (int t = 0; t < 4; ++t) {
      a00 += dot4(c[0][t], bf2f4(e40[t * 64 + lane]));
      a01 += dot4(c[0][t], bf2f4(e40[256 + t * 64 + lane]));
      a10 += dot4(c[1][t], bf2f4(e41[t * 64 + lane]));
      a11 += dot4(c[1][t], bf2f4(e41[256 + t * 64 + lane]));
    }
    const float o00 = wave_sum_bcast(a00) + ldsEb[best[0] * 2 + 0];
    const float o01 = wave_sum_bcast(a01) + ldsEb[best[0] * 2 + 1];
    const float o10 = wave_sum_bcast(a10) + ldsEb[best[1] * 2 + 0];
    const float o11 = wave_sum_bcast(a11) + ldsEb[best[1] * 2 + 1];

    if (lane == 0)
      ((float4*)out)[pp] = make_float4(o00, o01, o10, o11);
  }
}

extern "C" void kernel_launch(void* const* d_in, const int* in_sizes, int n_in,
                              void* d_out, int out_size, void* d_ws,
                              size_t ws_size, hipStream_t stream) {
  const float* cls = (const float*)d_in[0];
  const float* gate_w = (const float*)d_in[1];
  const float* gate_b = (const float*)d_in[2];
  const float* expert_w = (const float*)d_in[3];
  const float* expert_b = (const float*)d_in[4];
  float* out = (float*)d_out;

  // 512 blocks * 512 threads = 4096 waves, 16 pairs each (exact).
  hipLaunchKernelGGL(hardmoe_kernel, dim3(512), dim3(512), 0, stream, cls,
                     gate_w, gate_b, expert_w, expert_b, out);
}